// Round 6
// baseline (277.259 us; speedup 1.0000x reference)
//
#include <hip/hip_runtime.h>
#include <hip/hip_bf16.h>

#define DEVI __device__ __forceinline__

typedef __attribute__((ext_vector_type(8))) short bfrag8;  // 8 bf16 (4 VGPRs)
typedef __attribute__((ext_vector_type(4))) float f32x4;

constexpr int NROW = 8192;
constexpr int DDIM = 768;
constexpr int BM = 256, BN = 256, BK = 64;
constexpr int KT = DDIM / BK;              // 12 K-tiles
constexpr int SLOT_BYTES = BM * BK * 2;    // 32768 per A/B slot
constexpr int NTI = NROW / BM;             // 32
constexpr int NTJ = NROW / BN;             // 32

// ---- exact monotonic float<->uint key for atomicMax on floats ----
DEVI unsigned fkey(float f) {
  unsigned b = __float_as_uint(f);
  return (b & 0x80000000u) ? ~b : (b | 0x80000000u);
}
DEVI float funkey(unsigned k) {
  unsigned b = (k & 0x80000000u) ? (k ^ 0x80000000u) : ~k;
  return __uint_as_float(b);
}

DEVI short f2bf(float f) {
  __hip_bfloat16 h = __float2bfloat16(f);
  union { __hip_bfloat16 h; short s; } u;
  u.h = h;
  return u.s;
}

// ---------------------------------------------------------------------------
// K1: fp32 -> bf16 + row norms + rowmax init.  1 wave per row, vectorized.
// ---------------------------------------------------------------------------
__global__ __launch_bounds__(256) void prep_kernel(
    const float* __restrict__ ex, const float* __restrict__ ey,
    __hip_bfloat16* __restrict__ xh, __hip_bfloat16* __restrict__ yh,
    float* __restrict__ nx, float* __restrict__ ny,
    unsigned* __restrict__ rowmax)
{
  const int which = blockIdx.y;
  const float* __restrict__ src = which ? ey : ex;
  __hip_bfloat16* __restrict__ dst = which ? yh : xh;
  float* __restrict__ nrm = which ? ny : nx;

  const int wave = threadIdx.x >> 6, lane = threadIdx.x & 63;
  const int row = blockIdx.x * 4 + wave;
  const float* __restrict__ srow = src + (size_t)row * DDIM;
  __hip_bfloat16* __restrict__ drow = dst + (size_t)row * DDIM;

  float ss = 0.f;
#pragma unroll
  for (int it = 0; it < 3; ++it) {          // 3 * 256 floats = 768
    const int c = it * 256 + lane * 4;
    float4 v = *reinterpret_cast<const float4*>(srow + c);
    ss += v.x * v.x + v.y * v.y + v.z * v.z + v.w * v.w;
    short4 h;
    h.x = f2bf(v.x); h.y = f2bf(v.y); h.z = f2bf(v.z); h.w = f2bf(v.w);
    *reinterpret_cast<short4*>(drow + c) = h;
  }
#pragma unroll
  for (int off = 32; off > 0; off >>= 1) ss += __shfl_xor(ss, off, 64);
  if (lane == 0) {
    nrm[row] = sqrtf(ss);
    if (!which) rowmax[row] = 0u;  // below every real cosine key
  }
}

// ---------------------------------------------------------------------------
// K2: 256x256-tile 8-phase bf16 GEMM + fused 1/(nx*ny) scale + row-max.
// 8 waves (2M x 4N), BK=64, LDS = 4 slots x 32 KB (A/B x even/odd K-tile).
// Counted vmcnt(4) crosses barriers (T4); raw s_barrier (no vmcnt drain);
// setprio around MFMA clusters (T5); XOR 16B-chunk swizzle (T2, via
// pre-swizzled global source since global_load_lds writes linearly).
// ---------------------------------------------------------------------------

// Stage one half-tile (128 rows x 64 bf16 = 16 KB) global->LDS, 2 loads/thread.
DEVI void stage_half(const char* __restrict__ src, int row0, int kt, int half,
                     char* slot, int tid)
{
#pragma unroll
  for (int l = 0; l < 2; ++l) {
    const int idx = l * 512 + tid;
    const int r = idx >> 3;                  // row within half (0..127)
    const int jlog = (idx & 7) ^ (r & 7);    // logical 16B chunk to fetch
    const char* g = src + (size_t)(row0 + half * 128 + r) * (DDIM * 2)
                        + (size_t)(kt * BK * 2) + jlog * 16;
    char* d = slot + half * 16384 + idx * 16;  // linear dest (lane-contig)
    __builtin_amdgcn_global_load_lds(
        (const __attribute__((address_space(1))) void*)g,
        (__attribute__((address_space(3))) void*)d, 16, 0, 0);
  }
}

// Read one 16B MFMA fragment from a swizzled 256-row slot.
DEVI bfrag8 ld_frag(const char* slot, int r, int kchunk) {
  const int phys = kchunk ^ (r & 7);
  return *reinterpret_cast<const bfrag8*>(slot + r * 128 + phys * 16);
}

#define BAR() __builtin_amdgcn_s_barrier()
#define VMCNT4() asm volatile("s_waitcnt vmcnt(4)" ::: "memory")
#define VMCNT0() asm volatile("s_waitcnt vmcnt(0)" ::: "memory")

#define READ_A(SLOT, MH)                                                      \
  _Pragma("unroll") for (int mm = 0; mm < 4; ++mm) {                          \
    a8[mm][0] = ld_frag((SLOT), arow + (MH) * 64 + mm * 16, kc0);             \
    a8[mm][1] = ld_frag((SLOT), arow + (MH) * 64 + mm * 16, kc1);             \
  }

#define READ_B(SLOT, NH)                                                      \
  _Pragma("unroll") for (int nn = 0; nn < 2; ++nn) {                          \
    b8[(NH) * 2 + nn][0] = ld_frag((SLOT), brow + (NH) * 32 + nn * 16, kc0);  \
    b8[(NH) * 2 + nn][1] = ld_frag((SLOT), brow + (NH) * 32 + nn * 16, kc1);  \
  }

#define MFMA_QUAD(MH, NH)                                                     \
  __builtin_amdgcn_s_setprio(1);                                              \
  _Pragma("unroll") for (int mm = 0; mm < 4; ++mm)                            \
    _Pragma("unroll") for (int nn = 0; nn < 2; ++nn)                          \
      _Pragma("unroll") for (int kk = 0; kk < 2; ++kk)                        \
        acc[(MH) * 4 + mm][(NH) * 2 + nn] =                                   \
            __builtin_amdgcn_mfma_f32_16x16x32_bf16(                          \
                a8[mm][kk], b8[(NH) * 2 + nn][kk],                            \
                acc[(MH) * 4 + mm][(NH) * 2 + nn], 0, 0, 0);                  \
  __builtin_amdgcn_s_setprio(0);

__global__ __launch_bounds__(512, 2) void gemm_max_kernel(
    const __hip_bfloat16* __restrict__ xh, const __hip_bfloat16* __restrict__ yh,
    const float* __restrict__ nx, const float* __restrict__ ny,
    unsigned* __restrict__ rowmax)
{
  __shared__ __align__(16) char lds[4 * SLOT_BYTES];  // 128 KiB
  char* sA0 = lds;                       // A, even K-tiles
  char* sA1 = lds + SLOT_BYTES;          // A, odd
  char* sB0 = lds + 2 * SLOT_BYTES;      // B, even
  char* sB1 = lds + 3 * SLOT_BYTES;      // B, odd

  const int tid = threadIdx.x;
  const int lane = tid & 63;
  const int wave = tid >> 6;
  const int wr = wave >> 2;              // 0..1  (M split)
  const int wc = wave & 3;               // 0..3  (N split)

  const int l15 = lane & 15;
  const int khi = lane >> 4;             // 0..3
  const int kc0 = khi, kc1 = 4 + khi;    // kchunk for kk=0,1
  const int arow = wr * 128 + l15;
  const int brow = wc * 64 + l15;

  // XCD-aware block swizzle (1024 % 8 == 0 -> bijective)
  const int bid = blockIdx.x;
  const int swz = (bid & 7) * ((NTI * NTJ) / 8) + (bid >> 3);
  const int bi = swz >> 5;               // row tile (0..31)
  const int bj = swz & 31;               // col tile (0..31)
  const int birow = bi * BM, bjrow = bj * BN;

  const char* gx = (const char*)xh;
  const char* gy = (const char*)yh;

  f32x4 acc[8][4];
#pragma unroll
  for (int m = 0; m < 8; ++m)
#pragma unroll
    for (int n = 0; n < 4; ++n) acc[m][n] = f32x4{0.f, 0.f, 0.f, 0.f};

  bfrag8 a8[4][2], b8[4][2];

  // ---- prologue: stage A0, B0, B1 (12 loads/thread); leave B1 in flight ----
  stage_half(gx, birow, 0, 0, sA0, tid);
  stage_half(gx, birow, 0, 1, sA0, tid);
  stage_half(gy, bjrow, 0, 0, sB0, tid);
  stage_half(gy, bjrow, 0, 1, sB0, tid);
  stage_half(gy, bjrow, 1, 0, sB1, tid);
  stage_half(gy, bjrow, 1, 1, sB1, tid);
  VMCNT4();   // A0,B0 landed; B1's 4 loads may remain in flight
  BAR();

  // ---- main loop: iterations 0..4 (K-tiles t0=2i, t1=2i+1), all stages real
  for (int i = 0; i < 5; ++i) {
    const int t0 = 2 * i, t1 = 2 * i + 1;
    // P1: read A(t0) mh0 + B(t0) nh0; stage A(t1)h0
    READ_A(sA0, 0); READ_B(sB0, 0);
    stage_half(gx, birow, t1, 0, sA1, tid);
    BAR(); MFMA_QUAD(0, 0); BAR();
    // P2: read B(t0) nh1; stage A(t1)h1
    READ_B(sB0, 1);
    stage_half(gx, birow, t1, 1, sA1, tid);
    BAR(); MFMA_QUAD(0, 1); BAR();
    // P3: read A(t0) mh1; stage B(t0+2)h0
    READ_A(sA0, 1);
    stage_half(gy, bjrow, t0 + 2, 0, sB0, tid);
    BAR(); MFMA_QUAD(1, 0); BAR();
    // P4: stage B(t0+2)h1; gate next K-tile's reads
    stage_half(gy, bjrow, t0 + 2, 1, sB0, tid);
    BAR(); MFMA_QUAD(1, 1);
    VMCNT4();   // A(t1)+B(t1) landed; B(t0+2)'s 4 loads may remain
    BAR();
    // P5: read A(t1) mh0 + B(t1) nh0; stage A(t0+2)h0
    READ_A(sA1, 0); READ_B(sB1, 0);
    stage_half(gx, birow, t0 + 2, 0, sA0, tid);
    BAR(); MFMA_QUAD(0, 0); BAR();
    // P6: read B(t1) nh1; stage A(t0+2)h1
    READ_B(sB1, 1);
    stage_half(gx, birow, t0 + 2, 1, sA0, tid);
    BAR(); MFMA_QUAD(0, 1); BAR();
    // P7: read A(t1) mh1; stage B(t1+2)h0
    READ_A(sA1, 1);
    stage_half(gy, bjrow, t1 + 2, 0, sB1, tid);
    BAR(); MFMA_QUAD(1, 0); BAR();
    // P8: stage B(t1+2)h1; gate next iteration's reads
    stage_half(gy, bjrow, t1 + 2, 1, sB1, tid);
    BAR(); MFMA_QUAD(1, 1);
    VMCNT4();   // A(t0+2)+B(t0+2) landed; B(t1+2)'s 4 loads may remain
    BAR();
  }

  // ---- final iteration: t0=10, t1=11; only A(11) still needs staging ----
  {
    READ_A(sA0, 0); READ_B(sB0, 0);
    stage_half(gx, birow, 11, 0, sA1, tid);
    BAR(); MFMA_QUAD(0, 0); BAR();
    READ_B(sB0, 1);
    stage_half(gx, birow, 11, 1, sA1, tid);
    BAR(); MFMA_QUAD(0, 1); BAR();
    READ_A(sA0, 1);
    BAR(); MFMA_QUAD(1, 0); BAR();
    BAR(); MFMA_QUAD(1, 1);
    VMCNT0();   // A(11) must be fully landed (nothing else in flight)
    BAR();
    READ_A(sA1, 0); READ_B(sB1, 0);
    BAR(); MFMA_QUAD(0, 0); BAR();
    READ_B(sB1, 1);
    BAR(); MFMA_QUAD(0, 1); BAR();
    READ_A(sA1, 1);
    BAR(); MFMA_QUAD(1, 0); BAR();
    BAR(); MFMA_QUAD(1, 1);
  }

  // ---- epilogue: c = dot/max(nx*ny,eps); row-max over n; atomicMax ----
  // C/D layout (16x16x32): col = lane&15, row = (lane>>4)*4 + reg  [m89/m91]
  const int lrow = lane >> 4, lcol = lane & 15;
  float nyv[4];
#pragma unroll
  for (int n = 0; n < 4; ++n) nyv[n] = ny[bjrow + wc * 64 + n * 16 + lcol];
#pragma unroll
  for (int m = 0; m < 8; ++m) {
#pragma unroll
    for (int q = 0; q < 4; ++q) {
      const int gi = birow + wr * 128 + m * 16 + lrow * 4 + q;
      const float nxv = nx[gi];
      float mx = -4.0f;
#pragma unroll
      for (int n = 0; n < 4; ++n) {
        float c = acc[m][n][q] / fmaxf(nxv * nyv[n], 1e-8f);
        mx = fmaxf(mx, c);
      }
#pragma unroll
      for (int off = 1; off < 16; off <<= 1)
        mx = fmaxf(mx, __shfl_xor(mx, off, 64));
      if (lcol == 0) atomicMax(&rowmax[gi], fkey(mx));
    }
  }
}

// ---------------------------------------------------------------------------
// K3: lp = Normal(1, 0.3).log_prob(max_c); out = sum(exp(lp)*lp)
// ---------------------------------------------------------------------------
__global__ __launch_bounds__(256) void finish_kernel(
    const unsigned* __restrict__ rowmax, float* __restrict__ out)
{
  const int tid = threadIdx.x;
  float s = 0.f;
  for (int i = tid; i < NROW; i += 256) {
    float x = funkey(rowmax[i]);
    float z = (x - 1.0f) * (1.0f / 0.3f);
    // -log(0.3) - 0.5*log(2*pi) = 0.2850342711212634
    float lp = -0.5f * z * z + 0.2850342711212634f;
    float w = expf(lp);
    s += w * lp;
  }
#pragma unroll
  for (int off = 32; off > 0; off >>= 1) s += __shfl_xor(s, off, 64);
  __shared__ float red[4];
  if ((tid & 63) == 0) red[tid >> 6] = s;
  __syncthreads();
  if (tid == 0) out[0] = red[0] + red[1] + red[2] + red[3];
}

// ---------------------------------------------------------------------------
extern "C" void kernel_launch(void* const* d_in, const int* in_sizes, int n_in,
                              void* d_out, int out_size, void* d_ws, size_t ws_size,
                              hipStream_t stream)
{
  const float* ex = (const float*)d_in[0];
  const float* ey = (const float*)d_in[1];
  float* out = (float*)d_out;

  char* ws = (char*)d_ws;
  const size_t mat = (size_t)NROW * DDIM * 2;  // 12.58 MB per bf16 matrix
  __hip_bfloat16* xh = (__hip_bfloat16*)(ws);
  __hip_bfloat16* yh = (__hip_bfloat16*)(ws + mat);
  float* nx = (float*)(ws + 2 * mat);
  float* ny = (float*)(ws + 2 * mat + (size_t)NROW * 4);
  unsigned* rowmax = (unsigned*)(ws + 2 * mat + (size_t)2 * NROW * 4);
  // total ws use: ~25.3 MB

  prep_kernel<<<dim3(NROW / 4, 2), 256, 0, stream>>>(ex, ey, xh, yh,
                                                     nx, ny, rowmax);
  gemm_max_kernel<<<dim3(NTI * NTJ), 512, 0, stream>>>(xh, yh, nx, ny, rowmax);
  finish_kernel<<<1, 256, 0, stream>>>(rowmax, out);
}